// Round 6
// baseline (121.208 us; speedup 1.0000x reference)
//
#include <hip/hip_runtime.h>
#include <math.h>

#define N_POINTS 16384
#define CELLS_PER_CLOUD 4096        // 16^3 per cloud, cell edge = r = 1/16
#define N_CELLS 32768               // 8 clouds
#define CAP 16                      // bucket capacity; lambda~0.5/cell, P(>16)~1e-12
#define NBR_STRIDE 32               // max neighbor count (established: cnt<=32)

constexpr double R2D = 1.0 / 256.0; // (1/16)^2, exact in binary

// Cell-occupancy counters live in .bss (zero-init at module load), NOT in the
// workspace: the harness re-poisons ws every iteration. The last kernel
// (k_conv_bc) re-zeros g_cnt after the last read (k_search_a), restoring the
// all-zeros invariant for the next iteration's k_prep. No memset dispatch.
__device__ int g_cnt[N_CELLS];

// ---------------------------------------------------------------------------
// K1: output copies (pos, batch->float) + cell-bucket build + pos4 pack.
// ---------------------------------------------------------------------------
__global__ __launch_bounds__(256) void k_prep(const float* __restrict__ pos,
                                              const int* __restrict__ batch,
                                              float* __restrict__ out,
                                              float4* __restrict__ bucket,
                                              float4* __restrict__ pos4)
{
    int i = blockIdx.x * 256 + threadIdx.x;
    out[i]                = pos[i];                      // output 0: pos copy [N,3]
    out[i + N_POINTS]     = pos[i + N_POINTS];
    out[i + 2 * N_POINTS] = pos[i + 2 * N_POINTS];
    out[3 * N_POINTS + 32 * N_POINTS + i] = (float)batch[i];   // output 2

    float x = pos[3 * i], y = pos[3 * i + 1], z = pos[3 * i + 2];
    int ix = min(max((int)(x * 16.f), 0), 15);
    int iy = min(max((int)(y * 16.f), 0), 15);
    int iz = min(max((int)(z * 16.f), 0), 15);
    int cell = ((batch[i] * 16 + iz) * 16 + iy) * 16 + ix;
    pos4[i] = make_float4(x, y, z, __int_as_float(cell));
    int slot = atomicAdd(&g_cnt[cell], 1);
    if (slot < CAP) bucket[cell * CAP + slot] = make_float4(x, y, z, __int_as_float(i));
}

// ---------------------------------------------------------------------------
// K2: 27-cell radius search (fp64 test) fused with layer a (6->8->8).
// 32 threads per point, one cell each; 8 points x 256-thread blocks.
// (unchanged from round 5)
// ---------------------------------------------------------------------------
__global__ __launch_bounds__(256) void k_search_a(
    const float4* __restrict__ pos4, const float4* __restrict__ bucket,
    const float* __restrict__ W1, const float* __restrict__ b1,
    const float* __restrict__ W2, const float* __restrict__ b2,
    float* __restrict__ out_a, float4* __restrict__ nbr, int* __restrict__ nbr_cnt)
{
    __shared__ float sW1[48], sB1[8], sW2[64], sB2[8];
    __shared__ float4 s_hits[NBR_STRIDE][8];    // [slot][point] : 4 KB
    __shared__ int   s_k[8];
    __shared__ float s_mx[8][9];                // +1 pad

    int t = threadIdx.x;
    int p = t >> 5;          // point-in-block 0..7
    int g = t & 31;          // cell-group 0..31 (cells 0..26 active)

    if (t < 48) sW1[t] = W1[t];
    if (t < 8) { sB1[t] = b1[t]; sB2[t] = b2[t]; s_k[t] = 0; }
    if (t < 64) sW2[t] = W2[t];
    __syncthreads();

    int i = blockIdx.x * 8 + p;
    float4 pi4 = pos4[i];
    float xi = pi4.x, yi = pi4.y, zi = pi4.z;
    double xd = (double)xi, yd = (double)yi, zd = (double)zi;
    int cell0 = __float_as_int(pi4.w);
    int ix = cell0 & 15, iy = (cell0 >> 4) & 15, iz = (cell0 >> 8) & 15;
    int cb = cell0 & ~(CELLS_PER_CLOUD - 1);

    int dz = g / 9 - 1, dy = (g / 3) % 3 - 1, dx = g % 3 - 1;
    int zz = iz + dz, yy = iy + dy, xx = ix + dx;
    bool ok = (g < 27) & ((zz | yy | xx) >= 0) & (zz < 16) & (yy < 16) & (xx < 16);
    int zc = min(max(zz, 0), 15), yc = min(max(yy, 0), 15),
        xc = min(max(xx, 0), 15);
    int cid = cb + (zc << 8) + (yc << 4) + xc;       // always a valid address
    int nc = min(g_cnt[cid], CAP);                   // unconditional load
    int n = ok ? nc : 0;

    for (int s = 0; s < n; s++) {
        float4 q = bucket[cid * CAP + s];
        double ddx = xd - (double)q.x, ddy = yd - (double)q.y,
               ddz = zd - (double)q.z;
        double d2 = ddx * ddx + ddy * ddy + ddz * ddz;
        if (d2 <= R2D) {
            int slot = atomicAdd(&s_k[p], 1);
            if (slot < NBR_STRIDE) {
                s_hits[slot][p] = q;
                nbr[i * NBR_STRIDE + slot] = q;
            }
        }
    }
    __syncthreads();
    int kc = min(s_k[p], NBR_STRIDE);

    if (g == 0) nbr_cnt[i] = kc;

    if (g < 8) {
        float mxv = 0.f;                            // self always valid, relu >= 0
        for (int kk = 0; kk < kc; kk++) {
            float4 q = s_hits[kk][p];
            float in6[6] = { q.x, q.y, q.z, q.x - xi, q.y - yi, q.z - zi };
            float h = sB1[g];
#pragma unroll
            for (int c6 = 0; c6 < 6; c6++) h = fmaf(in6[c6], sW1[c6 * 8 + g], h);
            mxv = fmaxf(mxv, fmaxf(h, 0.f));
        }
        s_mx[p][g] = mxv;
    }
    __syncthreads();
    if (g < 8) {
        float o = sB2[g];
#pragma unroll
        for (int k = 0; k < 8; k++) o = fmaf(s_mx[p][k], sW2[k * 8 + g], o);
        out_a[i * 8 + g] = o > 0.f ? o : expm1f(o);   // celu, alpha=1
    }
}

// ---------------------------------------------------------------------------
// K3: FUSED conv_b + conv_c. Block owns 8 points. 1-hop redundant recompute:
// out_b[j] is recomputed locally for every neighbor j of the block's points
// (entries, avg ~26/block, max 256), using only previous-dispatch data
// (nbr, nbr_cnt, out_a) -> no grid sync needed, no global out_b buffer.
// conv_c then consumes LDS-resident s_b[p][slot][16] (no gather at all).
// Numerics: identical canonical neighbor lists + identical FMA order per
// channel + commutative/associative fmax agg -> bit-identical outputs.
// ---------------------------------------------------------------------------
__global__ __launch_bounds__(256) void k_conv_bc(
    const float4* __restrict__ pos4, const float4* __restrict__ out_a4,
    const float4* __restrict__ nbr, const int* __restrict__ nbr_cnt,
    const float* __restrict__ W1b, const float* __restrict__ b1b,
    const float* __restrict__ W2b, const float* __restrict__ b2b,
    const float* __restrict__ W1c, const float* __restrict__ b1c,
    const float* __restrict__ W2c, const float* __restrict__ b2c,
    float* __restrict__ out)
{
    __shared__ float4 s_q[8][NBR_STRIDE];        // own hit records (pos+id)   4 KB
    __shared__ int    s_cnt[8], s_base[9], s_ent[256];
    __shared__ float4 s_bq[16][NBR_STRIDE];      // chunk: entry-neighbor recs 8 KB
    __shared__ float4 s_ba[16][NBR_STRIDE][2];   // chunk: out_a of those     16 KB
    __shared__ float  s_gag[16][17];             // per-entry agg16 (+pad)
    __shared__ float  s_b[8][NBR_STRIDE][16];    // out_b per (p,slot)        16 KB
    __shared__ float  s_aggc[8][33];             // conv_c agg (+pad)

    int tid = threadIdx.x;

    // re-zero g_cnt for the next iteration (last kernel; g_cnt not read here)
    if (blockIdx.x < N_CELLS / 256) g_cnt[blockIdx.x * 256 + tid] = 0;

    // ---- load own neighbor lists + build compact entry list ----
    int p8 = tid >> 5, sl = tid & 31;
    int ip = blockIdx.x * 8 + p8;
    if (sl == 0) s_cnt[p8] = nbr_cnt[ip];
    s_q[p8][sl] = nbr[ip * NBR_STRIDE + sl];     // slots >= cnt: stale, unused
    __syncthreads();
    if (tid == 0) {
        int a = 0;
#pragma unroll
        for (int pp = 0; pp < 8; pp++) { s_base[pp] = a; a += s_cnt[pp]; }
        s_base[8] = a;
    }
    __syncthreads();
    if (sl < s_cnt[p8]) s_ent[s_base[p8] + sl] = (p8 << 8) | sl;
    __syncthreads();
    int L = s_base[8];                           // >= 8 (self always a hit)

    // ---- phase 1: out_b for every entry, chunks of 16 entries x 16 ch ----
    int lane_e = tid >> 4;       // 0..15 entry lane
    int me     = tid & 15;       // conv_b channel
    float wb1[11], wb2[16];
#pragma unroll
    for (int k = 0; k < 11; k++) wb1[k] = W1b[k * 16 + me];
#pragma unroll
    for (int k = 0; k < 16; k++) wb2[k] = W2b[k * 16 + me];
    float bb1 = b1b[me], bb2 = b2b[me];

    for (int eb = 0; eb < L; eb += 16) {
        int e = eb + lane_e;
        bool act = e < L;
        int pp = 0, ss = 0, j = 0, cj = 0;
        float4 qj = make_float4(0.f, 0.f, 0.f, 0.f);
        if (act) {
            int en = s_ent[e];
            pp = en >> 8; ss = en & 255;
            qj = s_q[pp][ss];
            j = __float_as_int(qj.w);
            cj = nbr_cnt[j];
        }
        // stage entry-neighbor records + their out_a features
#pragma unroll
        for (int h2 = 0; h2 < 2; h2++) {
            int kk = me + 16 * h2;
            if (act && kk < cj) {
                float4 qk = nbr[j * NBR_STRIDE + kk];
                s_bq[lane_e][kk] = qk;
                int kidx = __float_as_int(qk.w);
                s_ba[lane_e][kk][0] = out_a4[kidx * 2];
                s_ba[lane_e][kk][1] = out_a4[kidx * 2 + 1];
            }
        }
        __syncthreads();
        float mx = 0.f;                          // self always valid, relu >= 0
        if (act) {
            float xj = qj.x, yj = qj.y, zj = qj.z;
            for (int kk = 0; kk < cj; kk++) {
                float4 v0 = s_ba[lane_e][kk][0], v1 = s_ba[lane_e][kk][1];
                float4 qk = s_bq[lane_e][kk];
                float h = bb1;
                h = fmaf(v0.x, wb1[0], h);
                h = fmaf(v0.y, wb1[1], h);
                h = fmaf(v0.z, wb1[2], h);
                h = fmaf(v0.w, wb1[3], h);
                h = fmaf(v1.x, wb1[4], h);
                h = fmaf(v1.y, wb1[5], h);
                h = fmaf(v1.z, wb1[6], h);
                h = fmaf(v1.w, wb1[7], h);
                h = fmaf(qk.x - xj, wb1[8],  h);
                h = fmaf(qk.y - yj, wb1[9],  h);
                h = fmaf(qk.z - zj, wb1[10], h);
                mx = fmaxf(mx, fmaxf(h, 0.f));
            }
        }
        s_gag[lane_e][me] = mx;
        __syncthreads();
        if (act) {
            float o = bb2;
#pragma unroll
            for (int k = 0; k < 16; k++) o = fmaf(s_gag[lane_e][k], wb2[k], o);
            o = o > 0.f ? o : expm1f(o);         // celu, alpha=1
            s_b[pp][ss][me] = o;
        }
        __syncthreads();
    }

    // ---- phase 2: conv_c (16 -> 32 -> 32) from LDS-resident out_b ----
    int pc = tid >> 5, mc = tid & 31;
    int ic = blockIdx.x * 8 + pc;
    float4 pic = pos4[ic];
    int cntc = s_cnt[pc];
    float w1r[19], w2r[32];
#pragma unroll
    for (int k = 0; k < 19; k++) w1r[k] = W1c[k * 32 + mc];
#pragma unroll
    for (int k = 0; k < 32; k++) w2r[k] = W2c[k * 32 + mc];
    float bbc = b1c[mc];

    float mxv = 0.f;                             // self always valid, relu >= 0
    for (int tt = 0; tt < cntc; tt++) {
        float4 q = s_q[pc][tt];
        const float4* fb4 = (const float4*)&s_b[pc][tt][0];
        float4 f0 = fb4[0], f1 = fb4[1], f2 = fb4[2], f3 = fb4[3];
        float h = bbc;
        h = fmaf(f0.x, w1r[0],  h);
        h = fmaf(f0.y, w1r[1],  h);
        h = fmaf(f0.z, w1r[2],  h);
        h = fmaf(f0.w, w1r[3],  h);
        h = fmaf(f1.x, w1r[4],  h);
        h = fmaf(f1.y, w1r[5],  h);
        h = fmaf(f1.z, w1r[6],  h);
        h = fmaf(f1.w, w1r[7],  h);
        h = fmaf(f2.x, w1r[8],  h);
        h = fmaf(f2.y, w1r[9],  h);
        h = fmaf(f2.z, w1r[10], h);
        h = fmaf(f2.w, w1r[11], h);
        h = fmaf(f3.x, w1r[12], h);
        h = fmaf(f3.y, w1r[13], h);
        h = fmaf(f3.z, w1r[14], h);
        h = fmaf(f3.w, w1r[15], h);
        h = fmaf(q.x - pic.x, w1r[16], h);
        h = fmaf(q.y - pic.y, w1r[17], h);
        h = fmaf(q.z - pic.z, w1r[18], h);
        mxv = fmaxf(mxv, fmaxf(h, 0.f));
    }
    s_aggc[pc][mc] = mxv;
    __syncthreads();

    float o = b2c[mc];
#pragma unroll
    for (int k = 0; k < 32; k++) o = fmaf(s_aggc[pc][k], w2r[k], o);
    out[3 * N_POINTS + ic * 32 + mc] = o > 0.f ? o : expm1f(o);   // celu
}

// ---------------------------------------------------------------------------
extern "C" void kernel_launch(void* const* d_in, const int* in_sizes, int n_in,
                              void* d_out, int out_size, void* d_ws, size_t ws_size,
                              hipStream_t stream)
{
    const float* pos   = (const float*)d_in[0];
    // d_in[1] = rgb: unused by reference
    const int*   batch = (const int*)d_in[2];
    const float* W1a = (const float*)d_in[3];
    const float* b1a = (const float*)d_in[4];
    const float* W2a = (const float*)d_in[5];
    const float* b2a = (const float*)d_in[6];
    const float* W1b = (const float*)d_in[7];
    const float* b1b = (const float*)d_in[8];
    const float* W2b = (const float*)d_in[9];
    const float* b2b = (const float*)d_in[10];
    const float* W1c = (const float*)d_in[11];
    const float* b1c = (const float*)d_in[12];
    const float* W2c = (const float*)d_in[13];
    const float* b2c = (const float*)d_in[14];

    float* out = (float*)d_out;

    char* ws = (char*)d_ws;
    size_t off = 0;
    auto alloc = [&](size_t bytes) {
        char* p = ws + off; off += (bytes + 255) & ~size_t(255); return p;
    };
    float4* bucket  = (float4*)alloc((size_t)N_CELLS * CAP * 16);
    float4* pos4    = (float4*)alloc(N_POINTS * 16);
    int*    nbr_cnt = (int*)alloc(N_POINTS * 4);
    float4* nbr     = (float4*)alloc((size_t)N_POINTS * NBR_STRIDE * 16);
    float*  out_a   = (float*)alloc(N_POINTS * 8 * 4);

    hipLaunchKernelGGL(k_prep, dim3(N_POINTS / 256), dim3(256), 0, stream,
                       pos, batch, out, bucket, pos4);
    hipLaunchKernelGGL(k_search_a, dim3(N_POINTS / 8), dim3(256), 0, stream,
                       pos4, bucket, W1a, b1a, W2a, b2a,
                       out_a, nbr, nbr_cnt);
    hipLaunchKernelGGL(k_conv_bc, dim3(N_POINTS / 8), dim3(256), 0, stream,
                       pos4, (const float4*)out_a, nbr, nbr_cnt,
                       W1b, b1b, W2b, b2b, W1c, b1c, W2c, b2c, out);
}

// Round 8
// 110.586 us; speedup vs baseline: 1.0960x; 1.0960x over previous
//
#include <hip/hip_runtime.h>
#include <math.h>

#define N_POINTS 16384
#define CELLS_PER_CLOUD 4096        // 16^3 per cloud, cell edge = r = 1/16
#define N_CELLS 32768               // 8 clouds
#define CAP 16                      // bucket capacity; lambda~0.5/cell, P(>16)~1e-12
#define NBR_STRIDE 32               // max neighbor count (established: cnt<=32)

constexpr double R2D = 1.0 / 256.0; // (1/16)^2, exact in binary

// Cell-occupancy counters live in .bss (zero-init at module load), NOT in the
// workspace: the harness re-poisons ws every iteration. k_conv_c re-zeros
// g_cnt after the last read (k_search_a), restoring the all-zeros invariant
// for the next iteration's k_prep. No memset dispatch needed.
__device__ int g_cnt[N_CELLS];

// ---------------------------------------------------------------------------
// K1: output copies (pos, batch->float) + cell-bucket build + pos4 pack.
// 64 blocks x 256 = N_POINTS threads.
// ---------------------------------------------------------------------------
__global__ __launch_bounds__(256) void k_prep(const float* __restrict__ pos,
                                              const int* __restrict__ batch,
                                              float* __restrict__ out,
                                              float4* __restrict__ bucket,
                                              float4* __restrict__ pos4)
{
    int i = blockIdx.x * 256 + threadIdx.x;
    out[i]                = pos[i];                      // output 0: pos copy [N,3]
    out[i + N_POINTS]     = pos[i + N_POINTS];
    out[i + 2 * N_POINTS] = pos[i + 2 * N_POINTS];
    out[3 * N_POINTS + 32 * N_POINTS + i] = (float)batch[i];   // output 2

    float x = pos[3 * i], y = pos[3 * i + 1], z = pos[3 * i + 2];
    int ix = min(max((int)(x * 16.f), 0), 15);
    int iy = min(max((int)(y * 16.f), 0), 15);
    int iz = min(max((int)(z * 16.f), 0), 15);
    int cell = ((batch[i] * 16 + iz) * 16 + iy) * 16 + ix;
    pos4[i] = make_float4(x, y, z, __int_as_float(cell));
    int slot = atomicAdd(&g_cnt[cell], 1);
    if (slot < CAP) bucket[cell * CAP + slot] = make_float4(x, y, z, __int_as_float(i));
}

// ---------------------------------------------------------------------------
// K2: 27-cell radius search (fp64 test) fused with layer a (6->8->8).
// 16 threads per point (cells interleaved c = g + 16*cc), block = 512 threads
// = 32 points x 16 groups; 512 blocks -> 16 waves/CU. Hits compact via an
// LDS atomic slot counter; max-agg commutative -> order nondeterminism benign.
// Layer-a tail: 8 channel-threads per point (g<8), bit-identical FMA order.
// (best-measured configuration, round 4: 110.1 us)
// ---------------------------------------------------------------------------
__global__ __launch_bounds__(512) void k_search_a(
    const float4* __restrict__ pos4, const float4* __restrict__ bucket,
    const float* __restrict__ W1, const float* __restrict__ b1,
    const float* __restrict__ W2, const float* __restrict__ b2,
    float* __restrict__ out_a, float4* __restrict__ nbr, int* __restrict__ nbr_cnt)
{
    __shared__ float sW1[48], sB1[8], sW2[64], sB2[8];
    __shared__ float4 s_hits[NBR_STRIDE][32];   // [slot][point] : 16 KB
    __shared__ int   s_k[32];
    __shared__ float s_mx[32][9];               // +1 pad

    int t = threadIdx.x;
    int p = t & 31;          // point-in-block
    int g = t >> 5;          // cell-group 0..15

    if (t < 48) sW1[t] = W1[t];
    if (t < 8) { sB1[t] = b1[t]; sB2[t] = b2[t]; }
    if (t < 64) sW2[t] = W2[t];
    if (t < 32) s_k[t] = 0;
    __syncthreads();

    int i = blockIdx.x * 32 + p;
    float4 pi4 = pos4[i];
    float xi = pi4.x, yi = pi4.y, zi = pi4.z;
    double xd = (double)xi, yd = (double)yi, zd = (double)zi;
    int cell0 = __float_as_int(pi4.w);
    int ix = cell0 & 15, iy = (cell0 >> 4) & 15, iz = (cell0 >> 8) & 15;
    int cb = cell0 & ~(CELLS_PER_CLOUD - 1);

    // --- this thread's <=2 cells: counts, independent loads ---
    int n[2], cid[2];
#pragma unroll
    for (int cc = 0; cc < 2; cc++) {
        int c = g + 16 * cc;                      // 0..31; >=27 masked off
        int dz = c / 9 - 1, dy = (c / 3) % 3 - 1, dx = c % 3 - 1;
        int zz = iz + dz, yy = iy + dy, xx = ix + dx;
        bool ok = (c < 27) & ((zz | yy | xx) >= 0) & (zz < 16) & (yy < 16) & (xx < 16);
        int zc = min(max(zz, 0), 15), yc = min(max(yy, 0), 15),
            xc = min(max(xx, 0), 15);
        cid[cc] = cb + (zc << 8) + (yc << 4) + xc;   // always a valid address
        int nc = min(g_cnt[cid[cc]], CAP);           // unconditional load
        n[cc] = ok ? nc : 0;
    }
    int nmax = max(n[0], n[1]);

    // --- candidate rounds: load + fp64 test + LDS compact + global nbr store ---
    for (int s = 0; s < nmax; s++) {
#pragma unroll
        for (int cc = 0; cc < 2; cc++) {
            if (s < n[cc]) {
                float4 q = bucket[cid[cc] * CAP + s];
                double ddx = xd - (double)q.x, ddy = yd - (double)q.y,
                       ddz = zd - (double)q.z;
                double d2 = ddx * ddx + ddy * ddy + ddz * ddz;
                if (d2 <= R2D) {
                    int slot = atomicAdd(&s_k[p], 1);
                    if (slot < NBR_STRIDE) {
                        s_hits[slot][p] = q;
                        nbr[i * NBR_STRIDE + slot] = q;
                    }
                }
            }
        }
    }
    __syncthreads();
    int kc = min(s_k[p], NBR_STRIDE);

    if (g == 0) nbr_cnt[i] = kc;

    // --- layer-a: channel m = g, for g < 8 ---
    if (g < 8) {
        float mxv = 0.f;                            // self always valid, relu >= 0
        for (int kk = 0; kk < kc; kk++) {
            float4 q = s_hits[kk][p];
            float in6[6] = { q.x, q.y, q.z, q.x - xi, q.y - yi, q.z - zi };
            float h = sB1[g];
#pragma unroll
            for (int c6 = 0; c6 < 6; c6++) h = fmaf(in6[c6], sW1[c6 * 8 + g], h);
            mxv = fmaxf(mxv, fmaxf(h, 0.f));
        }
        s_mx[p][g] = mxv;
    }
    __syncthreads();
    if (g < 8) {
        float o = sB2[g];
#pragma unroll
        for (int k = 0; k < 8; k++) o = fmaf(s_mx[p][k], sW2[k * 8 + g], o);
        out_a[i * 8 + g] = o > 0.f ? o : expm1f(o);   // celu, alpha=1
    }
}

// ---------------------------------------------------------------------------
// K3/K4: PointNetConv, LDS-staged gather then per-(point,channel) compute.
// ZERO_CNT (conv_c only): re-zero g_cnt for the next iteration — runs after
// k_search_a's last read; visibility to next dispatch guaranteed at kernel end.
// ---------------------------------------------------------------------------
template<int CIN4, int CMID, int PTS, bool ZERO_CNT>
__global__ __launch_bounds__(256) void k_conv(
    const float4* __restrict__ pos4, const float4* __restrict__ xin4,
    const float4* __restrict__ nbr, const int* __restrict__ nbr_cnt,
    const float* __restrict__ W1, const float* __restrict__ b1,
    const float* __restrict__ W2, const float* __restrict__ b2,
    float* __restrict__ xout)
{
    constexpr int CIN = CIN4 * 4;
    __shared__ float4 s_q[PTS][NBR_STRIDE];           // neighbor pos+id
    __shared__ float4 s_x[PTS][NBR_STRIDE][CIN4];     // gathered features
    __shared__ float  s_agg[PTS][CMID + 1];           // +1 pad

    int tid = threadIdx.x;

    if (ZERO_CNT) {
        int gid = blockIdx.x * 256 + tid;
        if (gid < N_CELLS) g_cnt[gid] = 0;
    }

    // ---- phase 1: parallel gather into LDS ----
#pragma unroll
    for (int w = tid; w < PTS * NBR_STRIDE; w += 256) {
        int sp = w >> 5, slot = w & 31;
        int si = blockIdx.x * PTS + sp;
        if (slot < nbr_cnt[si]) {
            float4 q = nbr[si * NBR_STRIDE + slot];
            s_q[sp][slot] = q;
            int j = __float_as_int(q.w);
#pragma unroll
            for (int k = 0; k < CIN4; k++) s_x[sp][slot][k] = xin4[j * CIN4 + k];
        }
    }
    __syncthreads();

    // ---- phase 2: per-(point, channel) compute from LDS ----
    int p = tid / CMID;
    int m = tid % CMID;
    int i = blockIdx.x * PTS + p;

    float4 pi = pos4[i];
    int cnt = nbr_cnt[i];

    float w1c[CIN + 3];
#pragma unroll
    for (int k = 0; k < CIN + 3; k++) w1c[k] = W1[k * CMID + m];
    float w2c[CMID];
#pragma unroll
    for (int k = 0; k < CMID; k++) w2c[k] = W2[k * CMID + m];
    float bb = b1[m];

    float mxv = 0.f;                                  // self always valid, relu >= 0
    for (int t = 0; t < cnt; t++) {
        float4 q = s_q[p][t];
        float h = bb;
#pragma unroll
        for (int k = 0; k < CIN4; k++) {
            float4 v = s_x[p][t][k];
            h = fmaf(v.x, w1c[4 * k],     h);
            h = fmaf(v.y, w1c[4 * k + 1], h);
            h = fmaf(v.z, w1c[4 * k + 2], h);
            h = fmaf(v.w, w1c[4 * k + 3], h);
        }
        h = fmaf(q.x - pi.x, w1c[CIN],     h);
        h = fmaf(q.y - pi.y, w1c[CIN + 1], h);
        h = fmaf(q.z - pi.z, w1c[CIN + 2], h);
        mxv = fmaxf(mxv, fmaxf(h, 0.f));
    }
    s_agg[p][m] = mxv;
    __syncthreads();

    float o = b2[m];
#pragma unroll
    for (int k = 0; k < CMID; k++) o = fmaf(s_agg[p][k], w2c[k], o);
    xout[i * CMID + m] = o > 0.f ? o : expm1f(o);     // celu, alpha=1
}

// ---------------------------------------------------------------------------
extern "C" void kernel_launch(void* const* d_in, const int* in_sizes, int n_in,
                              void* d_out, int out_size, void* d_ws, size_t ws_size,
                              hipStream_t stream)
{
    const float* pos   = (const float*)d_in[0];
    // d_in[1] = rgb: unused by reference
    const int*   batch = (const int*)d_in[2];
    const float* W1a = (const float*)d_in[3];
    const float* b1a = (const float*)d_in[4];
    const float* W2a = (const float*)d_in[5];
    const float* b2a = (const float*)d_in[6];
    const float* W1b = (const float*)d_in[7];
    const float* b1b = (const float*)d_in[8];
    const float* W2b = (const float*)d_in[9];
    const float* b2b = (const float*)d_in[10];
    const float* W1c = (const float*)d_in[11];
    const float* b1c = (const float*)d_in[12];
    const float* W2c = (const float*)d_in[13];
    const float* b2c = (const float*)d_in[14];

    float* out = (float*)d_out;

    char* ws = (char*)d_ws;
    size_t off = 0;
    auto alloc = [&](size_t bytes) {
        char* p = ws + off; off += (bytes + 255) & ~size_t(255); return p;
    };
    float4* bucket  = (float4*)alloc((size_t)N_CELLS * CAP * 16);
    float4* pos4    = (float4*)alloc(N_POINTS * 16);
    int*    nbr_cnt = (int*)alloc(N_POINTS * 4);
    float4* nbr     = (float4*)alloc((size_t)N_POINTS * NBR_STRIDE * 16);
    float*  out_a   = (float*)alloc(N_POINTS * 8 * 4);
    float*  out_b   = (float*)alloc(N_POINTS * 16 * 4);

    hipLaunchKernelGGL(k_prep, dim3(N_POINTS / 256), dim3(256), 0, stream,
                       pos, batch, out, bucket, pos4);
    hipLaunchKernelGGL(k_search_a, dim3(N_POINTS / 32), dim3(512), 0, stream,
                       pos4, bucket, W1a, b1a, W2a, b2a,
                       out_a, nbr, nbr_cnt);
    hipLaunchKernelGGL((k_conv<2, 16, 16, false>), dim3(N_POINTS / 16), dim3(256), 0, stream,
                       pos4, (const float4*)out_a, nbr, nbr_cnt,
                       W1b, b1b, W2b, b2b, out_b);
    hipLaunchKernelGGL((k_conv<4, 32, 8, true>), dim3(N_POINTS / 8), dim3(256), 0, stream,
                       pos4, (const float4*)out_b, nbr, nbr_cnt,
                       W1c, b1c, W2c, b2c, out + 3 * N_POINTS);
}